// Round 6
// baseline (123.521 us; speedup 1.0000x reference)
//
#include <hip/hip_runtime.h>
#include <stdint.h>
#include <stddef.h>

// Match numpy float32 rounding: forbid fma contraction in all float math below.
#pragma clang fp contract(off)

#define N8   819200u
#define N16  204800u
#define N32  51200u
#define NTOT 1075200u
#define TOPK 2048
#define CAND_MAX 8192
#define NBIN 8192u
#define BINSHIFT 10
#define NMS_THR 0.4f
#define DET_THR 0.5f

// ws byte offsets
#define OFF_HIST   0u        // u32[8192]    32KB
#define OFF_META   32768u    // u32[16]
#define OFF_CAND   32832u    // u64[8192]    64KB
#define OFF_TIDX   98368u    // u32[2048]
#define OFF_TCONF  106560u   // f32[2048]
#define OFF_BOX    114752u   // f32[2048*4]  (16B aligned)
#define OFF_DIAG   147520u   // u32[2048]    8KB
#define OFF_SUPPT  155968u   // u32[64][64][32] = 512KB, [chunk][colword][row]

__device__ __forceinline__ float load_conf(unsigned a, const float* __restrict__ s8,
                                           const float* __restrict__ s16,
                                           const float* __restrict__ s32) {
  if (a < N8) return s8[a];
  if (a < N8 + N16) return s16[a - N8];
  return s32[a - (N8 + N16)];
}

__device__ __forceinline__ void decode(unsigned a,
    const float* __restrict__ b8, const float* __restrict__ l8,
    const float* __restrict__ b16, const float* __restrict__ l16,
    const float* __restrict__ b32, const float* __restrict__ l32,
    float& cx, float& cy, float& s, const float*& bb, const float*& lm) {
  if (a < N8) {
    unsigned cell = a >> 1;
    cx = (float)((cell % 640u) * 8u); cy = (float)((cell / 640u) * 8u);
    s = 8.f; bb = b8 + (size_t)a * 4; lm = l8 + (size_t)a * 10;
  } else if (a < N8 + N16) {
    unsigned loc = a - N8; unsigned cell = loc >> 1;
    cx = (float)((cell % 320u) * 16u); cy = (float)((cell / 320u) * 16u);
    s = 16.f; bb = b16 + (size_t)loc * 4; lm = l16 + (size_t)loc * 10;
  } else {
    unsigned loc = a - (N8 + N16); unsigned cell = loc >> 1;
    cx = (float)((cell % 160u) * 32u); cy = (float)((cell / 160u) * 32u);
    s = 32.f; bb = b32 + (size_t)loc * 4; lm = l32 + (size_t)loc * 10;
  }
}

// K1: histogram of conf>=0.5 on 13-bit prefix of (bits - bits(0.5))
__global__ void k_hist(const float* __restrict__ s8, const float* __restrict__ s16,
                       const float* __restrict__ s32, unsigned* __restrict__ hist) {
  unsigned i = blockIdx.x * blockDim.x + threadIdx.x;
  unsigned st = gridDim.x * blockDim.x;
  for (unsigned a = i; a < NTOT; a += st) {
    float c = load_conf(a, s8, s16, s32);
    if (c >= DET_THR) {
      unsigned v = (__float_as_uint(c) - 0x3F000000u) >> BINSHIFT;
      if (v > NBIN - 1u) v = NBIN - 1u;
      atomicAdd(&hist[v], 1u);
    }
  }
}

// K2: find cutoff prefix (smallest p with suffix-count >= TOPK); single WG
__global__ void __launch_bounds__(1024) k_scan(const unsigned* __restrict__ hist,
                                               unsigned* __restrict__ meta) {
  __shared__ unsigned suf[1024];
  int t = threadIdx.x;
  const unsigned* hp = hist + (size_t)t * 8;
  unsigned s = 0;
  for (int b = 0; b < 8; b++) s += hp[b];
  suf[t] = s;
  __syncthreads();
  for (int d = 1; d < 1024; d <<= 1) {
    unsigned v = (t + d < 1024) ? suf[t + d] : 0u;
    __syncthreads();
    suf[t] += v;
    __syncthreads();
  }
  unsigned total = suf[0];
  unsigned mine = suf[t];
  unsigned nxt = (t < 1023) ? suf[t + 1] : 0u;
  if (total < (unsigned)TOPK) {
    if (t == 0) { meta[0] = 0u; meta[2] = total; }
    return;
  }
  if (mine >= (unsigned)TOPK && nxt < (unsigned)TOPK) {
    unsigned run = nxt, cut = (unsigned)t * 8u;
    for (int b = 7; b >= 0; b--) {
      run += hp[b];
      if (run >= (unsigned)TOPK) { cut = (unsigned)t * 8u + (unsigned)b; break; }
    }
    meta[0] = cut; meta[2] = total;
  }
}

// K3: compact candidates (>= cutoff prefix) as 64-bit sort keys
__global__ void k_compact(const float* __restrict__ s8, const float* __restrict__ s16,
                          const float* __restrict__ s32, unsigned* __restrict__ meta,
                          unsigned long long* __restrict__ cand) {
  unsigned cut = meta[0];
  unsigned i = blockIdx.x * blockDim.x + threadIdx.x;
  unsigned st = gridDim.x * blockDim.x;
  for (unsigned a = i; a < NTOT; a += st) {
    float c = load_conf(a, s8, s16, s32);
    if (c >= DET_THR) {
      unsigned b = __float_as_uint(c);
      unsigned v = (b - 0x3F000000u) >> BINSHIFT;
      if (v >= cut) {
        unsigned pos = atomicAdd(&meta[3], 1u);
        if (pos < (unsigned)CAND_MAX)
          cand[pos] = ((unsigned long long)b << 32) |
                      (unsigned long long)(0xFFFFFFFFu - a);
      }
    }
  }
}

// K4: rank-and-scatter. Keys unique -> rank(x)=#{y>x} is a permutation.
__global__ void __launch_bounds__(256) k_rank(
    const unsigned long long* __restrict__ cand, const unsigned* __restrict__ meta,
    const float* __restrict__ b8, const float* __restrict__ l8,
    const float* __restrict__ b16, const float* __restrict__ l16,
    const float* __restrict__ b32, const float* __restrict__ l32,
    const float* __restrict__ dsp,
    unsigned* __restrict__ tidx, float* __restrict__ tconf, float* __restrict__ box) {
  unsigned count = meta[3];
  if (count > (unsigned)CAND_MAX) count = (unsigned)CAND_MAX;
  unsigned wave = blockIdx.x * 4u + (threadIdx.x >> 6);
  unsigned lane = threadIdx.x & 63u;
  if (wave >= count) return;
  unsigned long long my = cand[wave];
  unsigned cnt = 0;
  for (unsigned i = lane; i < count; i += 64u)
    cnt += (cand[i] > my) ? 1u : 0u;
  for (int d = 32; d > 0; d >>= 1) cnt += __shfl_down(cnt, d);
  if (lane == 0 && cnt < (unsigned)TOPK) {
    unsigned r = cnt;
    unsigned a = 0xFFFFFFFFu - (unsigned)(my & 0xFFFFFFFFull);
    float conf = __uint_as_float((unsigned)(my >> 32));
    float cx, cy, s; const float* bb; const float* lm;
    decode(a, b8, l8, b16, l16, b32, l32, cx, cy, s, bb, lm);
    float ds = dsp[0];
    float b0 = bb[0] * s, b1 = bb[1] * s, b2 = bb[2] * s, b3 = bb[3] * s;
    box[r * 4 + 0] = (cx - b0) / ds;
    box[r * 4 + 1] = (cy - b1) / ds;
    box[r * 4 + 2] = (cx + b2) / ds;
    box[r * 4 + 3] = (cy + b3) / ds;
    tidx[r] = a; tconf[r] = conf;
  }
}

// K5: suppression matrix, transposed for NMS: supp_t[chunk i>>5][colword w][row i&31],
// bit[i][j] = (iou > thr) && (j > i). Also diag32[i] = the u32 word j in
// [32*(i>>5), 32*(i>>5)+32) of row i (the chunk-diagonal word).
__global__ void __launch_bounds__(256) k_supp(const float* __restrict__ box,
                                              unsigned* __restrict__ supp_t,
                                              unsigned* __restrict__ diag32) {
  int i = blockIdx.x;
  const float4 bi = ((const float4*)box)[i];
  float ai = fmaxf(bi.z - bi.x, 0.f) * fmaxf(bi.w - bi.y, 0.f);
  int tid = threadIdx.x;
  int lane = tid & 63, wv = tid >> 6;
  int c = i >> 5, k = i & 31;
  for (int base = 0; base < TOPK; base += 256) {
    int j = base + tid;
    const float4 bj = ((const float4*)box)[j];
    float aj = fmaxf(bj.z - bj.x, 0.f) * fmaxf(bj.w - bj.y, 0.f);
    float ltx = fmaxf(bi.x, bj.x), lty = fmaxf(bi.y, bj.y);
    float rbx = fminf(bi.z, bj.z), rby = fminf(bi.w, bj.w);
    float w = fmaxf(rbx - ltx, 0.f), h = fmaxf(rby - lty, 0.f);
    float inter = w * h;
    float iou = inter / (ai + aj - inter + 1e-9f);
    bool pred = (iou > NMS_THR) && (j > i);
    unsigned long long word = __ballot(pred);
    int w64 = (base >> 6) + wv;
    if (lane == 0) {
      supp_t[c * 2048 + (2 * w64) * 32 + k]     = (unsigned)(word & 0xFFFFFFFFull);
      supp_t[c * 2048 + (2 * w64 + 1) * 32 + k] = (unsigned)(word >> 32);
      if (w64 == (i >> 6))
        diag32[i] = (unsigned)(word >> (((i >> 5) & 1) * 32));
    }
  }
}

// K6: greedy NMS (wave 0) + output decode/write (all 256 threads).
// Keep mask: lane l owns u32 word covering j in [32l, 32l+32).
// Per chunk c: closure over diag words runs fully SCALAR (readfirstlane forces
// SGPR; chain is s_bitcmp/s_cselect/s_andn2), then bulk apply with scalar
// masks via v_and_or_b32. Supp rows quad-buffered as 8x dwordx4 per chunk.
__global__ void __launch_bounds__(256) k_nms_out(
    const unsigned* __restrict__ supp_t, const unsigned* __restrict__ diag32,
    const unsigned* __restrict__ meta,
    const unsigned* __restrict__ tidx, const float* __restrict__ tconf,
    const float* __restrict__ b8, const float* __restrict__ l8,
    const float* __restrict__ b16, const float* __restrict__ l16,
    const float* __restrict__ b32, const float* __restrict__ l32,
    const float* __restrict__ dsp, float* __restrict__ out) {
  __shared__ unsigned keepw[64];
  int tid = threadIdx.x;
  if (tid < 64) {
    int lane = tid;
    unsigned count = meta[3];
    if (count > (unsigned)TOPK) count = (unsigned)TOPK;
    unsigned lo = (unsigned)lane * 32u;
    unsigned kw = (count >= lo + 32u) ? 0xFFFFFFFFu
                : (count <= lo ? 0u : ((1u << (count - lo)) - 1u));
    const uint4* rp4 = (const uint4*)supp_t + (size_t)lane * 8;
    uint4 T0[8], T1[8], T2[8], T3[8];
    unsigned dga[32], dgb[32];

#define LOADT(BUF, C)                                                         \
  _Pragma("unroll") for (int q = 0; q < 8; q++)                               \
      BUF[q] = rp4[(size_t)((C) * 512 + q)];
#define LOADD(DBUF, C)                                                        \
  _Pragma("unroll") for (int k = 0; k < 32; k++)                              \
      DBUF[k] = diag32[(unsigned)((C) * 32 + k)];

    LOADT(T0, 0) LOADT(T1, 1) LOADT(T2, 2) LOADT(T3, 3)
    LOADD(dga, 0)

#define STEP(BUF, DCUR, DNXT, C)                                              \
  {                                                                           \
    unsigned w = __builtin_amdgcn_readlane(kw, (C));                          \
    _Pragma("unroll") for (int k = 0; k < 32; k++) {                          \
      unsigned d = __builtin_amdgcn_readfirstlane(DCUR[k]);                   \
      w &= ~(((w >> k) & 1u) ? d : 0u);                                       \
    }                                                                         \
    if ((C) + 1 < 64) { LOADD(DNXT, (C) + 1) }                                \
    unsigned acc = 0u;                                                        \
    _Pragma("unroll") for (int q = 0; q < 8; q++) {                           \
      unsigned m0 = (unsigned)((int)(w << (31 - (4 * q + 0))) >> 31);         \
      unsigned m1 = (unsigned)((int)(w << (31 - (4 * q + 1))) >> 31);         \
      unsigned m2 = (unsigned)((int)(w << (31 - (4 * q + 2))) >> 31);         \
      unsigned m3 = (unsigned)((int)(w << (31 - (4 * q + 3))) >> 31);         \
      acc |= BUF[q].x & m0;                                                   \
      acc |= BUF[q].y & m1;                                                   \
      acc |= BUF[q].z & m2;                                                   \
      acc |= BUF[q].w & m3;                                                   \
    }                                                                         \
    kw &= ~acc;                                                               \
    if ((C) + 4 < 64) { LOADT(BUF, (C) + 4) }                                 \
  }

#pragma unroll 1
    for (int c = 0; c < 64; c += 8) {
      STEP(T0, dga, dgb, c + 0)
      STEP(T1, dgb, dga, c + 1)
      STEP(T2, dga, dgb, c + 2)
      STEP(T3, dgb, dga, c + 3)
      STEP(T0, dga, dgb, c + 4)
      STEP(T1, dgb, dga, c + 5)
      STEP(T2, dga, dgb, c + 6)
      STEP(T3, dgb, dga, c + 7)
    }
#undef LOADT
#undef LOADD
#undef STEP
    keepw[lane] = kw;
  }
  __syncthreads();
  float ds = dsp[0];
  for (int r = tid; r < TOPK; r += 256) {
    bool kept = (keepw[r >> 5] >> (r & 31)) & 1u;
    float o[15];
    if (kept) {
      unsigned a = tidx[r];
      float cx, cy, s; const float* bb; const float* lm;
      decode(a, b8, l8, b16, l16, b32, l32, cx, cy, s, bb, lm);
      o[0] = tconf[r];
      float b0 = bb[0] * s, b1 = bb[1] * s, b2 = bb[2] * s, b3 = bb[3] * s;
      o[1] = (cx - b0) / ds;
      o[2] = (cy - b1) / ds;
      o[3] = (cx + b2) / ds;
      o[4] = (cy + b3) / ds;
      for (int p = 0; p < 5; p++) {
        float lx = lm[2 * p] * s, ly = lm[2 * p + 1] * s;
        o[5 + 2 * p] = (cx + lx) / ds;
        o[6 + 2 * p] = (cy + ly) / ds;
      }
    } else {
      for (int cc = 0; cc < 15; cc++) o[cc] = 0.f;
    }
    for (int cc = 0; cc < 15; cc++) out[(size_t)r * 15 + cc] = o[cc];
  }
}

extern "C" void kernel_launch(void* const* d_in, const int* in_sizes, int n_in,
                              void* d_out, int out_size, void* d_ws, size_t ws_size,
                              hipStream_t stream) {
  const float* s8  = (const float*)d_in[0];
  const float* b8  = (const float*)d_in[1];
  const float* l8  = (const float*)d_in[2];
  const float* s16 = (const float*)d_in[3];
  const float* b16 = (const float*)d_in[4];
  const float* l16 = (const float*)d_in[5];
  const float* s32 = (const float*)d_in[6];
  const float* b32 = (const float*)d_in[7];
  const float* l32 = (const float*)d_in[8];
  const float* dsp = (const float*)d_in[9];
  char* ws = (char*)d_ws;
  unsigned* hist = (unsigned*)(ws + OFF_HIST);
  unsigned* meta = (unsigned*)(ws + OFF_META);
  unsigned long long* cand = (unsigned long long*)(ws + OFF_CAND);
  unsigned* tidx = (unsigned*)(ws + OFF_TIDX);
  float* tconf = (float*)(ws + OFF_TCONF);
  float* box = (float*)(ws + OFF_BOX);
  unsigned* diag = (unsigned*)(ws + OFF_DIAG);
  unsigned* supp_t = (unsigned*)(ws + OFF_SUPPT);
  float* out = (float*)d_out;

  hipMemsetAsync(ws, 0, OFF_META + 64, stream);  // hist + meta
  k_hist<<<2048, 256, 0, stream>>>(s8, s16, s32, hist);
  k_scan<<<1, 1024, 0, stream>>>(hist, meta);
  k_compact<<<2048, 256, 0, stream>>>(s8, s16, s32, meta, cand);
  k_rank<<<CAND_MAX / 4, 256, 0, stream>>>(cand, meta, b8, l8, b16, l16, b32, l32,
                                           dsp, tidx, tconf, box);
  k_supp<<<TOPK, 256, 0, stream>>>(box, supp_t, diag);
  k_nms_out<<<1, 256, 0, stream>>>(supp_t, diag, meta, tidx, tconf,
                                   b8, l8, b16, l16, b32, l32, dsp, out);
}